// Round 8
// baseline (293.665 us; speedup 1.0000x reference)
//
#include <hip/hip_runtime.h>
#include <hip/hip_fp16.h>
#include <math.h>

#define NN 50000
#define NE 800000
#define HC 128
#define EMB 64
#define STATS_BLOCKS 64
#define NB 196           // buckets of 256 nodes
#define HIST_BLOCKS 196  // ceil(NE/4096)
#define WPREP_BLOCKS 192 // 3 layers x 64 blocks
#define WT_ROW 136       // padded fp16 W^T row (halves)
#define GEMM_BLOCKS 782  // ceil(NN/64)

typedef _Float16 f16x8 __attribute__((ext_vector_type(8)));
typedef float f32x4 __attribute__((ext_vector_type(4)));

__device__ __forceinline__ float lrelu(float x) { return x > 0.0f ? x : 0.2f * x; }
__device__ __forceinline__ float gelu_f(float x) {
    return 0.5f * x * (1.0f + erff(x * 0.70710678118654752440f));
}
__device__ __forceinline__ float sel4(float4 v, int h) {
    float r = v.x;
    r = (h == 1) ? v.y : r;
    r = (h == 2) ? v.z : r;
    r = (h == 3) ? v.w : r;
    return r;
}
__device__ __forceinline__ f16x8 cvt8(float4 a, float4 b) {
    f16x8 v;
    v[0] = (_Float16)a.x; v[1] = (_Float16)a.y; v[2] = (_Float16)a.z; v[3] = (_Float16)a.w;
    v[4] = (_Float16)b.x; v[5] = (_Float16)b.y; v[6] = (_Float16)b.z; v[7] = (_Float16)b.w;
    return v;
}

// ---- fused frontend: stats | bucket histogram (dst>>8) | W->fp16 W^T prep ----
__global__ void prep_kernel(const float* __restrict__ rq, float* __restrict__ stats,
                            const int* __restrict__ dst, int* __restrict__ bucketCnt,
                            const float* __restrict__ W0, const float* __restrict__ W1,
                            const float* __restrict__ W2, _Float16* __restrict__ wt) {
    __shared__ float ls[4], ls2[4];
    __shared__ int cnt[NB];
    if (blockIdx.x < STATS_BLOCKS) {
        int i = blockIdx.x * 256 + threadIdx.x;
        float s = 0.f, s2 = 0.f;
        for (; i < NN; i += STATS_BLOCKS * 256) {
            float v = rq[i];
            s += v; s2 += v * v;
        }
        #pragma unroll
        for (int off = 32; off > 0; off >>= 1) {
            s  += __shfl_down(s, off);
            s2 += __shfl_down(s2, off);
        }
        int lane = threadIdx.x & 63, wid = threadIdx.x >> 6;
        if (lane == 0) { ls[wid] = s; ls2[wid] = s2; }
        __syncthreads();
        if (threadIdx.x == 0) {
            atomicAdd(&stats[0], ls[0] + ls[1] + ls[2] + ls[3]);
            atomicAdd(&stats[1], ls2[0] + ls2[1] + ls2[2] + ls2[3]);
        }
    } else if (blockIdx.x < STATS_BLOCKS + HIST_BLOCKS) {
        int bb = blockIdx.x - STATS_BLOCKS;
        for (int i = threadIdx.x; i < NB; i += 256) cnt[i] = 0;
        __syncthreads();
        int base = bb * 4096;
        #pragma unroll
        for (int it = 0; it < 16; it++) {
            int i = base + it * 256 + threadIdx.x;
            if (i < NE) atomicAdd(&cnt[dst[i] >> 8], 1);
        }
        __syncthreads();
        for (int i = threadIdx.x; i < NB; i += 256)
            if (cnt[i]) atomicAdd(&bucketCnt[i], cnt[i]);
    } else {
        int bb = blockIdx.x - STATS_BLOCKS - HIST_BLOCKS;   // 0..191
        int l = bb >> 6, blk = bb & 63;
        const float* W = (l == 0) ? W0 : (l == 1) ? W1 : W2;
        int idx = blk * 256 + threadIdx.x;   // 0..16383
        int n = idx >> 7, k = idx & 127;
        wt[(size_t)l * 128 * WT_ROW + n * WT_ROW + k] = (_Float16)W[k * 128 + n];
    }
}

// ---- in-block inclusive scan of bucketCnt into sIncl[256] ----
__device__ __forceinline__ void scan_buckets(const int* __restrict__ bucketCnt,
                                             int* sIncl /*LDS[256]*/) {
    int t = threadIdx.x;
    int v = (t < NB) ? bucketCnt[t] : 0;
    sIncl[t] = v;
    __syncthreads();
    #pragma unroll
    for (int off = 1; off < 256; off <<= 1) {
        int add = (t >= off) ? sIncl[t - off] : 0;
        __syncthreads();
        sIncl[t] += add;
        __syncthreads();
    }
}

// ---- MFMA + epilogue (shared): C from sX@sWt(B in LDS); h store + als/ald ----
__device__ __forceinline__ void mfma_epilogue(_Float16* sWt, _Float16* sX,
        const float* __restrict__ a_src, const float* __restrict__ a_dst,
        __half* __restrict__ h, float* __restrict__ als, float* __restrict__ ald,
        int row0) {
    int t = threadIdx.x;
    int w = t >> 6, l = t & 63;
    int col = l & 15, quad = l >> 4;

    f16x8 afr[4];
    #pragma unroll
    for (int ks = 0; ks < 4; ks++)
        afr[ks] = *(const f16x8*)&sX[(w * 16 + col) * WT_ROW + ks * 32 + quad * 8];

    f32x4 zero = {0.f, 0.f, 0.f, 0.f};
    f32x4 acc[8];
    #pragma unroll
    for (int nt = 0; nt < 8; nt++) acc[nt] = zero;
    #pragma unroll
    for (int nt = 0; nt < 8; nt++) {
        #pragma unroll
        for (int ks = 0; ks < 4; ks++) {
            f16x8 bfr = *(const f16x8*)&sWt[(nt * 16 + col) * WT_ROW + ks * 32 + quad * 8];
            acc[nt] = __builtin_amdgcn_mfma_f32_16x16x32_f16(afr[ks], bfr, acc[nt], 0, 0, 0);
        }
    }
    __syncthreads();   // all MFMA reads of sWt done; reuse as transpose buffer

    _Float16* sOut = sWt;   // [64][136]
    #pragma unroll
    for (int nt = 0; nt < 8; nt++)
        #pragma unroll
        for (int r = 0; r < 4; r++)
            sOut[(w * 16 + quad * 4 + r) * WT_ROW + nt * 16 + col] = (_Float16)acc[nt][r];
    __builtin_amdgcn_wave_barrier();
    #pragma unroll
    for (int i = 0; i < 4; i++) {
        int u = l + 64 * i;          // 0..255
        int r = u >> 4, off = (u & 15) * 8;
        int rr = row0 + w * 16 + r;
        f16x8 v = *(const f16x8*)&sOut[(w * 16 + r) * WT_ROW + off];
        if (rr < NN) *(f16x8*)(h + (size_t)rr * 128 + off) = v;
    }

    float as[8], ad[8];
    #pragma unroll
    for (int nt = 0; nt < 8; nt++) {
        as[nt] = a_src[nt * 16 + col];
        ad[nt] = a_dst[nt * 16 + col];
    }
    #pragma unroll
    for (int r = 0; r < 4; r++) {
        float ps[4], pd[4];
        #pragma unroll
        for (int hd = 0; hd < 4; hd++) {
            ps[hd] = acc[2 * hd][r] * as[2 * hd] + acc[2 * hd + 1][r] * as[2 * hd + 1];
            pd[hd] = acc[2 * hd][r] * ad[2 * hd] + acc[2 * hd + 1][r] * ad[2 * hd + 1];
            ps[hd] += __shfl_xor(ps[hd], 1); pd[hd] += __shfl_xor(pd[hd], 1);
            ps[hd] += __shfl_xor(ps[hd], 2); pd[hd] += __shfl_xor(pd[hd], 2);
            ps[hd] += __shfl_xor(ps[hd], 4); pd[hd] += __shfl_xor(pd[hd], 4);
            ps[hd] += __shfl_xor(ps[hd], 8); pd[hd] += __shfl_xor(pd[hd], 8);
        }
        int rr = row0 + w * 16 + quad * 4 + r;
        if (col == 0 && rr < NN) {
            *(float4*)(als + (size_t)rr * 4) = make_float4(ps[0], ps[1], ps[2], ps[3]);
            *(float4*)(ald + (size_t)rr * 4) = make_float4(pd[0], pd[1], pd[2], pd[3]);
        }
    }
}

// ---- fused dispatch: [gemm0 (x build + GEMM) | binA edge partition] ----
__launch_bounds__(256)
__global__ void gemm0_binA_kernel(const _Float16* __restrict__ wt,
                                  const float* __restrict__ a_src, const float* __restrict__ a_dst,
                                  __half* __restrict__ h, float* __restrict__ als,
                                  float* __restrict__ ald,
                                  const int* __restrict__ label, const float* __restrict__ rq,
                                  const float* __restrict__ emb, const float* __restrict__ reqW,
                                  const float* __restrict__ reqb, const float* __restrict__ stats,
                                  const int* __restrict__ src, const int* __restrict__ dst,
                                  const int* __restrict__ bucketCnt, int* __restrict__ gcur,
                                  int2* __restrict__ edge_tmp) {
    extern __shared__ char smem[];
    if (blockIdx.x >= GEMM_BLOCKS) {
        // -------- binA: partition edges into bucket regions --------
        int bb = blockIdx.x - GEMM_BLOCKS;
        int* sIncl  = (int*)smem;        // 256
        int* sBaseE = sIncl + 256;       // 256
        int* cnt    = sBaseE + 256;      // NB
        int* cur    = cnt + NB;          // NB
        int t = threadIdx.x;
        scan_buckets(bucketCnt, sIncl);
        {
            int v = (t < NB) ? bucketCnt[t] : 0;
            sBaseE[t] = sIncl[t] - v;
        }
        for (int i = t; i < NB; i += 256) cnt[i] = 0;
        __syncthreads();
        int base = bb * 4096;
        int d[16], s[16];
        #pragma unroll
        for (int it = 0; it < 16; it++) {
            int i = base + it * 256 + t;
            bool ok = i < NE;
            d[it] = ok ? dst[i] : -1;
            s[it] = ok ? src[i] : 0;
            if (ok) atomicAdd(&cnt[d[it] >> 8], 1);
        }
        __syncthreads();
        for (int i = t; i < NB; i += 256)
            cur[i] = cnt[i] ? (sBaseE[i] + atomicAdd(&gcur[i], cnt[i])) : 0;
        __syncthreads();
        #pragma unroll
        for (int it = 0; it < 16; it++) {
            if (d[it] >= 0) {
                int b = d[it] >> 8;
                int pos = atomicAdd(&cur[b], 1);
                edge_tmp[pos] = make_int2(s[it], d[it] & 255);
            }
        }
        return;
    }
    // -------- gemm0: build x in LDS from raw inputs, then GEMM --------
    _Float16* sWt = (_Float16*)smem;            // [128][136]
    _Float16* sX  = sWt + 128 * WT_ROW;         // [64][136]
    int t = threadIdx.x;
    int row0 = blockIdx.x * 64;

    {
        const f16x8* g = (const f16x8*)wt;
        f16x8* s = (f16x8*)sWt;
        #pragma unroll
        for (int i = 0; i < 9; i++) {
            int idx = t + 256 * i;
            if (idx < 128 * WT_ROW / 8) s[idx] = g[idx];
        }
    }
    {
        float sum = stats[0], sumsq = stats[1];
        float mean = sum / (float)NN;
        float var = (sumsq - sum * sum / (float)NN) / (float)(NN - 1);
        float inv = 1.0f / (sqrtf(var) + 1e-6f);
        #pragma unroll
        for (int i = 0; i < 4; i++) {
            int idx = t + 256 * i;   // 0..1023 8-half units
            int r = idx >> 4;        // 0..63
            int q = idx & 15;
            int rr = row0 + r;
            f16x8 v;
            #pragma unroll
            for (int j = 0; j < 8; j++) v[j] = (_Float16)0.f;
            if (rr < NN) {
                if (q < 8) {
                    const float4* er = (const float4*)(emb + (size_t)label[rr] * EMB);
                    v = cvt8(er[q * 2], er[q * 2 + 1]);
                } else {
                    int j4 = (q - 8) * 2;
                    float4 w0 = ((const float4*)reqW)[j4],     b0 = ((const float4*)reqb)[j4];
                    float4 w1 = ((const float4*)reqW)[j4 + 1], b1 = ((const float4*)reqb)[j4 + 1];
                    float r2 = (rq[rr] - mean) * inv;
                    v = cvt8(make_float4(r2 * w0.x + b0.x, r2 * w0.y + b0.y,
                                         r2 * w0.z + b0.z, r2 * w0.w + b0.w),
                             make_float4(r2 * w1.x + b1.x, r2 * w1.y + b1.y,
                                         r2 * w1.z + b1.z, r2 * w1.w + b1.w));
                }
            }
            *(f16x8*)&sX[r * WT_ROW + q * 8] = v;
        }
    }
    __syncthreads();
    mfma_epilogue(sWt, sX, a_src, a_dst, h, als, ald, row0);
}

// ------- binB: per-bucket local counting sort -> row_start + src_sorted -------
__global__ void binB_kernel(const int2* __restrict__ edge_tmp, const int* __restrict__ bucketCnt,
                            int* __restrict__ row_start, int* __restrict__ src_sorted) {
    __shared__ int sIncl[256];
    __shared__ int ldeg[256];
    __shared__ int lexcl[256];
    __shared__ int lcur[256];
    __shared__ int s_base, s_end;
    int b = blockIdx.x, t = threadIdx.x;
    scan_buckets(bucketCnt, sIncl);
    if (t == 0) {
        s_end = sIncl[b];
        s_base = sIncl[b] - bucketCnt[b];
    }
    ldeg[t] = 0;
    __syncthreads();
    int base = s_base, endb = s_end;
    for (int i = base + t; i < endb; i += 256)
        atomicAdd(&ldeg[edge_tmp[i].y], 1);
    __syncthreads();
    int v = ldeg[t];
    lexcl[t] = v;
    __syncthreads();
    #pragma unroll
    for (int off = 1; off < 256; off <<= 1) {
        int add = (t >= off) ? lexcl[t - off] : 0;
        __syncthreads();
        lexcl[t] += add;
        __syncthreads();
    }
    int excl = lexcl[t] - v;
    int node = b * 256 + t;
    if (node <= NN) row_start[node] = base + excl;
    lcur[t] = excl;
    __syncthreads();
    for (int i = base + t; i < endb; i += 256) {
        int2 e = edge_tmp[i];
        int pos = atomicAdd(&lcur[e.y], 1);
        src_sorted[base + pos] = e.x;
    }
}

// ---- fused layer, SINGLE-WAVE blocks, ROUND-PIPELINED ----
// Phase A: all 4 rounds' window-0 batch loads issued together (8 src loads,
// 8 als gathers all in flight -> 4x batch MLP); per-round LDS banks.
// Phase B: 4 consumes back-to-back (no barriers between rounds).
// Rare >128-edge spans handled by in-place restash (correct, ~never taken).
// LDS = sX 4352 + lds_sp 16640 = 21 KB -> 7 blocks/CU >= ~6 demand.
__launch_bounds__(64, 3)
__global__ void layer_fused_kernel(const __half* __restrict__ hp, const float* __restrict__ alsp,
                                   const float* __restrict__ aldp, const int* __restrict__ row_start,
                                   const int* __restrict__ src_sorted, const float* __restrict__ biasp,
                                   const _Float16* __restrict__ wt,
                                   const float* __restrict__ a_src, const float* __restrict__ a_dst,
                                   __half* __restrict__ ho, float* __restrict__ also_,
                                   float* __restrict__ aldo) {
    __shared__ _Float16 sX[16 * WT_ROW];     // 4352 B (agg out = GEMM A; reused as sOut)
    __shared__ int2 lds_sp[4][4][130];       // 16640 B [round][head][slot]
    int lane = threadIdx.x;                  // 0..63
    int g    = lane >> 4;   // node sub-index in round == quad in GEMM
    int cg   = lane & 15;   // channel group       == col  in GEMM
    int c0   = cg * 8;
    int head = cg >> 2;
    int row0 = blockIdx.x * 16;              // 3125 blocks * 16 = 50000 exactly

    int rsA[4], reA[4], stA[4], enA[4];
    float pselfA[4];

    // ---- Phase A: stash window0 of all 4 rounds (pipelined) ----
    #pragma unroll
    for (int r = 0; r < 4; r++) {
        int nb = row0 + r * 4;
        int node = nb + g;
        int rs = row_start[node];
        int re = row_start[node + 1];
        rsA[r] = rs; reA[r] = re;
        int start = __shfl(rs, 0);
        int end   = __shfl(re, 48);
        stA[r] = start; enA[r] = end;
        int b1 = __shfl(rs, 16), b2 = __shfl(rs, 32), b3 = __shfl(rs, 48);

        float4 adv = *(const float4*)(aldp + (size_t)node * 4);
        float4 avs = *(const float4*)(alsp + (size_t)node * 4);
        pselfA[r] = __expf(lrelu(sel4(avs, head) + sel4(adv, head)));

        if (start < end) {
            int j0 = start + lane, j1 = start + 64 + lane;
            bool v0 = j0 < end, v1 = j1 < end;
            int my0 = v0 ? src_sorted[j0] : 0;
            int my1 = v1 ? src_sorted[j1] : 0;
            float4 av0 = *(const float4*)(alsp + (size_t)my0 * 4);
            float4 av1 = *(const float4*)(alsp + (size_t)my1 * 4);
            int o0 = (j0 >= b1) + (j0 >= b2) + (j0 >= b3);
            int o1 = (j1 >= b1) + (j1 >= b2) + (j1 >= b3);
            float4 d0 = *(const float4*)(aldp + (size_t)(nb + (o0 > 3 ? 3 : o0)) * 4);
            float4 d1 = *(const float4*)(aldp + (size_t)(nb + (o1 > 3 ? 3 : o1)) * 4);
            lds_sp[r][0][lane] = make_int2(my0, __float_as_int(__expf(lrelu(av0.x + d0.x))));
            lds_sp[r][1][lane] = make_int2(my0, __float_as_int(__expf(lrelu(av0.y + d0.y))));
            lds_sp[r][2][lane] = make_int2(my0, __float_as_int(__expf(lrelu(av0.z + d0.z))));
            lds_sp[r][3][lane] = make_int2(my0, __float_as_int(__expf(lrelu(av0.w + d0.w))));
            lds_sp[r][0][64 + lane] = make_int2(my1, __float_as_int(__expf(lrelu(av1.x + d1.x))));
            lds_sp[r][1][64 + lane] = make_int2(my1, __float_as_int(__expf(lrelu(av1.y + d1.y))));
            lds_sp[r][2][64 + lane] = make_int2(my1, __float_as_int(__expf(lrelu(av1.z + d1.z))));
            lds_sp[r][3][64 + lane] = make_int2(my1, __float_as_int(__expf(lrelu(av1.w + d1.w))));
        }
    }
    __builtin_amdgcn_wave_barrier();

    // ---- Phase B: consume all 4 rounds back-to-back ----
    #pragma unroll
    for (int r = 0; r < 4; r++) {
        int nb = row0 + r * 4;
        int node = nb + g;
        int rs = rsA[r], re = reA[r];
        float s_sum = pselfA[r];
        float acc[8];
        {
            f16x8 hv = *(const f16x8*)((const char*)hp + (size_t)node * 256 + c0 * 2);
            #pragma unroll
            for (int j = 0; j < 8; j++) acc[j] = (float)hv[j] * pselfA[r];
        }

        for (int base = stA[r]; base < enA[r]; base += 128) {
            if (base != stA[r]) {
                // rare: restash next window for this round
                int b1 = __shfl(rs, 16), b2 = __shfl(rs, 32), b3 = __shfl(rs, 48);
                int end = enA[r];
                int j0 = base + lane, j1 = base + 64 + lane;
                bool v0 = j0 < end, v1 = j1 < end;
                int my0 = v0 ? src_sorted[j0] : 0;
                int my1 = v1 ? src_sorted[j1] : 0;
                float4 av0 = *(const float4*)(alsp + (size_t)my0 * 4);
                float4 av1 = *(const float4*)(alsp + (size_t)my1 * 4);
                int o0 = (j0 >= b1) + (j0 >= b2) + (j0 >= b3);
                int o1 = (j1 >= b1) + (j1 >= b2) + (j1 >= b3);
                float4 d0 = *(const float4*)(aldp + (size_t)(nb + (o0 > 3 ? 3 : o0)) * 4);
                float4 d1 = *(const float4*)(aldp + (size_t)(nb + (o1 > 3 ? 3 : o1)) * 4);
                __builtin_amdgcn_wave_barrier();
                lds_sp[r][0][lane] = make_int2(my0, __float_as_int(__expf(lrelu(av0.x + d0.x))));
                lds_sp[r][1][lane] = make_int2(my0, __float_as_int(__expf(lrelu(av0.y + d0.y))));
                lds_sp[r][2][lane] = make_int2(my0, __float_as_int(__expf(lrelu(av0.z + d0.z))));
                lds_sp[r][3][lane] = make_int2(my0, __float_as_int(__expf(lrelu(av0.w + d0.w))));
                lds_sp[r][0][64 + lane] = make_int2(my1, __float_as_int(__expf(lrelu(av1.x + d1.x))));
                lds_sp[r][1][64 + lane] = make_int2(my1, __float_as_int(__expf(lrelu(av1.y + d1.y))));
                lds_sp[r][2][64 + lane] = make_int2(my1, __float_as_int(__expf(lrelu(av1.z + d1.z))));
                lds_sp[r][3][64 + lane] = make_int2(my1, __float_as_int(__expf(lrelu(av1.w + d1.w))));
                __builtin_amdgcn_wave_barrier();
            }

            int lo  = rs > base ? rs : base;
            int hiw = base + 128;
            int hi  = re < hiw ? re : hiw;
            for (int k = lo; k < hi; k += 16) {
                float p[16];
                int off[16];
                #pragma unroll
                for (int i = 0; i < 16; i++) {
                    int e = k + i;
                    bool val = e < hi;
                    int ec = (val ? e : hi - 1) - base;
                    int2 sp = lds_sp[r][head][ec];
                    p[i] = val ? __int_as_float(sp.y) : 0.f;
                    off[i] = sp.x * 256 + c0 * 2;   // byte offset (fits 32-bit)
                }
                f16x8 raw[16];
                #pragma unroll
                for (int i = 0; i < 16; i++)
                    raw[i] = *(const f16x8*)((const char*)hp + off[i]);
                #pragma unroll
                for (int i = 0; i < 16; i++) {
                    s_sum += p[i];
                    #pragma unroll
                    for (int jj = 0; jj < 8; jj++)
                        acc[jj] += (float)raw[i][jj] * p[i];
                }
            }
        }

        float invs = 1.0f / (s_sum + 1e-16f);
        float4 bv0 = *(const float4*)(biasp + c0);
        float4 bv1 = *(const float4*)(biasp + c0 + 4);
        float ob[8] = {bv0.x, bv0.y, bv0.z, bv0.w, bv1.x, bv1.y, bv1.z, bv1.w};
        f16x8 o;
        #pragma unroll
        for (int jj = 0; jj < 8; jj++)
            o[jj] = (_Float16)gelu_f(acc[jj] * invs + ob[jj]);
        *(f16x8*)&sX[(r * 4 + g) * WT_ROW + c0] = o;
    }
    __builtin_amdgcn_wave_barrier();

    // ---- GEMM phase: A from sX (rows 0..15), B from L2-hot global wt ----
    int col = cg, quad = g;
    f16x8 afr[4];
    #pragma unroll
    for (int ks = 0; ks < 4; ks++)
        afr[ks] = *(const f16x8*)&sX[col * WT_ROW + ks * 32 + quad * 8];
    __builtin_amdgcn_wave_barrier();

    f32x4 zero = {0.f, 0.f, 0.f, 0.f};
    f32x4 acc2[8];
    #pragma unroll
    for (int nt = 0; nt < 8; nt++) acc2[nt] = zero;
    #pragma unroll
    for (int nt = 0; nt < 8; nt++) {
        #pragma unroll
        for (int ks = 0; ks < 4; ks++) {
            f16x8 bfr = *(const f16x8*)&wt[(nt * 16 + col) * WT_ROW + ks * 32 + quad * 8];
            acc2[nt] = __builtin_amdgcn_mfma_f32_16x16x32_f16(afr[ks], bfr, acc2[nt], 0, 0, 0);
        }
    }

    // transpose via sX rows (A-frags already consumed)
    _Float16* sOut = sX;
    #pragma unroll
    for (int nt = 0; nt < 8; nt++)
        #pragma unroll
        for (int r = 0; r < 4; r++)
            sOut[(quad * 4 + r) * WT_ROW + nt * 16 + col] = (_Float16)acc2[nt][r];
    __builtin_amdgcn_wave_barrier();
    #pragma unroll
    for (int i = 0; i < 4; i++) {
        int u = lane + 64 * i;       // 0..255 = 16 rows x 16 col-groups
        int r = u >> 4, off2 = (u & 15) * 8;
        int rr = row0 + r;
        f16x8 v = *(const f16x8*)&sOut[r * WT_ROW + off2];
        if (rr < NN) *(f16x8*)(ho + (size_t)rr * 128 + off2) = v;
    }

    float as[8], ad[8];
    #pragma unroll
    for (int nt = 0; nt < 8; nt++) {
        as[nt] = a_src[nt * 16 + col];
        ad[nt] = a_dst[nt * 16 + col];
    }
    #pragma unroll
    for (int r = 0; r < 4; r++) {
        float ps[4], pd[4];
        #pragma unroll
        for (int hd = 0; hd < 4; hd++) {
            ps[hd] = acc2[2 * hd][r] * as[2 * hd] + acc2[2 * hd + 1][r] * as[2 * hd + 1];
            pd[hd] = acc2[2 * hd][r] * ad[2 * hd] + acc2[2 * hd + 1][r] * ad[2 * hd + 1];
            ps[hd] += __shfl_xor(ps[hd], 1); pd[hd] += __shfl_xor(pd[hd], 1);
            ps[hd] += __shfl_xor(ps[hd], 2); pd[hd] += __shfl_xor(pd[hd], 2);
            ps[hd] += __shfl_xor(ps[hd], 4); pd[hd] += __shfl_xor(pd[hd], 4);
            ps[hd] += __shfl_xor(ps[hd], 8); pd[hd] += __shfl_xor(pd[hd], 8);
        }
        int rr = row0 + quad * 4 + r;
        if (col == 0 && rr < NN) {
            *(float4*)(also_ + (size_t)rr * 4) = make_float4(ps[0], ps[1], ps[2], ps[3]);
            *(float4*)(aldo + (size_t)rr * 4) = make_float4(pd[0], pd[1], pd[2], pd[3]);
        }
    }
}

// ---------------- final per-node softmax aggregation -> fp32 out ----------------
__launch_bounds__(256)
__global__ void agg_final_kernel(const __half* __restrict__ h, const float* __restrict__ als_,
                                 const float* __restrict__ ald_, const int* __restrict__ row_start,
                                 const int* __restrict__ src_sorted, const float* __restrict__ bias,
                                 float* __restrict__ outf) {
    __shared__ int2 lds_sp[4][4][130];   // [wave][head][slot] = {src, p_bits}
    int wid  = threadIdx.x >> 6;
    int lane = threadIdx.x & 63;
    int g    = lane >> 4;
    int cg   = lane & 15;
    int c0   = cg * 8;
    int head = cg >> 2;

    int nb = blockIdx.x * 16 + wid * 4;   // 3125 blocks * 16 = 50000 exactly
    if (nb >= NN) return;
    int node = nb + g;

    int rs = row_start[node];
    int re = row_start[node + 1];
    int start = __shfl(rs, 0);
    int end   = __shfl(re, 48);
    int b1 = __shfl(rs, 16), b2 = __shfl(rs, 32), b3 = __shfl(rs, 48);

    float4 adv = *(const float4*)(ald_ + (size_t)node * 4);
    float4 avs = *(const float4*)(als_ + (size_t)node * 4);

    float p_self = __expf(lrelu(sel4(avs, head) + sel4(adv, head)));
    float s_sum = p_self;
    float acc[8];
    {
        f16x8 hv = *(const f16x8*)(h + (size_t)node * 128 + c0);
        #pragma unroll
        for (int j = 0; j < 8; j++) acc[j] = (float)hv[j] * p_self;
    }

    for (int base = start; base < end; base += 128) {
        int j0 = base + lane, j1 = base + 64 + lane;
        bool v0 = j0 < end, v1 = j1 < end;
        int my0 = v0 ? src_sorted[j0] : 0;
        int my1 = v1 ? src_sorted[j1] : 0;
        float4 av0 = *(const float4*)(als_ + (size_t)my0 * 4);
        float4 av1 = *(const float4*)(als_ + (size_t)my1 * 4);
        int o0 = (j0 >= b1) + (j0 >= b2) + (j0 >= b3);
        int o1 = (j1 >= b1) + (j1 >= b2) + (j1 >= b3);
        float4 d0 = *(const float4*)(ald_ + (size_t)(nb + (o0 > 3 ? 3 : o0)) * 4);
        float4 d1 = *(const float4*)(ald_ + (size_t)(nb + (o1 > 3 ? 3 : o1)) * 4);
        lds_sp[wid][0][lane] = make_int2(my0, __float_as_int(__expf(lrelu(av0.x + d0.x))));
        lds_sp[wid][1][lane] = make_int2(my0, __float_as_int(__expf(lrelu(av0.y + d0.y))));
        lds_sp[wid][2][lane] = make_int2(my0, __float_as_int(__expf(lrelu(av0.z + d0.z))));
        lds_sp[wid][3][lane] = make_int2(my0, __float_as_int(__expf(lrelu(av0.w + d0.w))));
        lds_sp[wid][0][64 + lane] = make_int2(my1, __float_as_int(__expf(lrelu(av1.x + d1.x))));
        lds_sp[wid][1][64 + lane] = make_int2(my1, __float_as_int(__expf(lrelu(av1.y + d1.y))));
        lds_sp[wid][2][64 + lane] = make_int2(my1, __float_as_int(__expf(lrelu(av1.z + d1.z))));
        lds_sp[wid][3][64 + lane] = make_int2(my1, __float_as_int(__expf(lrelu(av1.w + d1.w))));
        __builtin_amdgcn_wave_barrier();

        int lo  = rs > base ? rs : base;
        int hiw = base + 128;
        int hi  = re < hiw ? re : hiw;
        for (int k = lo; k < hi; k += 16) {
            float p[16];
            const __half* ap[16];
            #pragma unroll
            for (int i = 0; i < 16; i++) {
                int e = k + i;
                bool val = e < hi;
                int ec = (val ? e : hi - 1) - base;
                int2 sp = lds_sp[wid][head][ec];
                p[i] = val ? __int_as_float(sp.y) : 0.f;
                ap[i] = h + (size_t)sp.x * 128 + c0;
            }
            f16x8 raw[16];
            #pragma unroll
            for (int i = 0; i < 16; i++)
                raw[i] = *(const f16x8*)ap[i];
            #pragma unroll
            for (int i = 0; i < 16; i++) {
                s_sum += p[i];
                #pragma unroll
                for (int jj = 0; jj < 8; jj++)
                    acc[jj] += (float)raw[i][jj] * p[i];
            }
        }
        __builtin_amdgcn_wave_barrier();
    }

    float invs = 1.0f / (s_sum + 1e-16f);
    float4 bv0 = *(const float4*)(bias + c0);
    float4 bv1 = *(const float4*)(bias + c0 + 4);
    float ob[8] = {bv0.x, bv0.y, bv0.z, bv0.w, bv1.x, bv1.y, bv1.z, bv1.w};
    float o8[8];
    #pragma unroll
    for (int jj = 0; jj < 8; jj++) o8[jj] = gelu_f(acc[jj] * invs + ob[jj]);
    float* op = outf + (size_t)node * 128 + c0;
    *(float4*)op       = make_float4(o8[0], o8[1], o8[2], o8[3]);
    *(float4*)(op + 4) = make_float4(o8[4], o8[5], o8[6], o8[7]);
}

extern "C" void kernel_launch(void* const* d_in, const int* in_sizes, int n_in,
                              void* d_out, int out_size, void* d_ws, size_t ws_size,
                              hipStream_t stream) {
    const int*   label = (const int*)d_in[0];
    const int*   eidx  = (const int*)d_in[1];          // [2, NE]
    const float* rq    = (const float*)d_in[3];
    const float* emb   = (const float*)d_in[4];
    const float* reqW  = (const float*)d_in[5];
    const float* reqb  = (const float*)d_in[6];
    const float* W[3]    = {(const float*)d_in[7],  (const float*)d_in[11], (const float*)d_in[15]};
    const float* asrc[3] = {(const float*)d_in[8],  (const float*)d_in[12], (const float*)d_in[16]};
    const float* adst[3] = {(const float*)d_in[9],  (const float*)d_in[13], (const float*)d_in[17]};
    const float* bias[3] = {(const float*)d_in[10], (const float*)d_in[14], (const float*)d_in[18]};

    const int* e_src = eidx;
    const int* e_dst = eidx + NE;

    char* ws = (char*)d_ws;
    size_t off = 0;
    auto A = [&](size_t n) { size_t o = off; off += (n + 255) & ~(size_t)255; return o; };
    size_t o_bcnt  = A(256 * 4);               // zeroed
    size_t o_gcur  = A(256 * 4);               // zeroed
    size_t o_stats = A(8);                     // zeroed
    size_t zero_bytes = off;
    size_t o_row   = A((size_t)(NN + 1) * 4);
    size_t o_etmp  = A((size_t)NE * 8);
    size_t o_srcS  = A((size_t)NE * 4);
    size_t o_wt    = A((size_t)3 * 128 * WT_ROW * 2);
    size_t o_h0    = A((size_t)NN * 128 * 2);  // fp16
    size_t o_h1    = A((size_t)NN * 128 * 2);  // fp16
    size_t o_als0  = A((size_t)NN * 4 * 4);
    size_t o_ald0  = A((size_t)NN * 4 * 4);
    size_t o_als1  = A((size_t)NN * 4 * 4);
    size_t o_ald1  = A((size_t)NN * 4 * 4);
    (void)ws_size; (void)n_in; (void)in_sizes; (void)out_size;

    int*      bcnt  = (int*)(ws + o_bcnt);
    int*      gcur  = (int*)(ws + o_gcur);
    float*    stats = (float*)(ws + o_stats);
    int*      rowst = (int*)(ws + o_row);
    int2*     etmp  = (int2*)(ws + o_etmp);
    int*      srcS  = (int*)(ws + o_srcS);
    _Float16* wt    = (_Float16*)(ws + o_wt);
    __half*   h0    = (__half*)(ws + o_h0);
    __half*   h1    = (__half*)(ws + o_h1);
    float*    als0  = (float*)(ws + o_als0);
    float*    ald0  = (float*)(ws + o_ald0);
    float*    als1  = (float*)(ws + o_als1);
    float*    ald1  = (float*)(ws + o_ald1);

    (void)hipMemsetAsync(ws, 0, zero_bytes, stream);

    const int smem_l0 = (128 + 64) * WT_ROW * 2;   // 52224 B

    // 1) stats | bucket histogram | W^T fp16 prep
    prep_kernel<<<STATS_BLOCKS + HIST_BLOCKS + WPREP_BLOCKS, 256, 0, stream>>>(
        rq, stats, e_dst, bcnt, W[0], W[1], W[2], wt);
    // 2) [gemm0 | binA]  (both depend only on prep; independent of each other)
    gemm0_binA_kernel<<<GEMM_BLOCKS + HIST_BLOCKS, 256, smem_l0, stream>>>(
        wt, asrc[0], adst[0], h0, als0, ald0, label, rq, emb, reqW, reqb, stats,
        e_src, e_dst, bcnt, gcur, etmp);
    // 3) binB: per-bucket counting sort -> row_start + src_sorted
    binB_kernel<<<NB, 256, 0, stream>>>(etmp, bcnt, rowst, srcS);
    // 4) fused layer 1 (round-pipelined): agg(h0) -> gemm(W1) -> h1
    layer_fused_kernel<<<(NN + 15) / 16, 64, 0, stream>>>(
        h0, als0, ald0, rowst, srcS, bias[0],
        wt + (size_t)1 * 128 * WT_ROW, asrc[1], adst[1], h1, als1, ald1);
    // 5) fused layer 2 (round-pipelined): agg(h1) -> gemm(W2) -> h0
    layer_fused_kernel<<<(NN + 15) / 16, 64, 0, stream>>>(
        h1, als1, ald1, rowst, srcS, bias[1],
        wt + (size_t)2 * 128 * WT_ROW, asrc[2], adst[2], h0, als0, ald0);
    // 6) final agg -> fp32 output
    agg_final_kernel<<<(NN + 15) / 16, 256, 0, stream>>>(
        h0, als0, ald0, rowst, srcS, bias[2], (float*)d_out);
}

// Round 9
// 283.271 us; speedup vs baseline: 1.0367x; 1.0367x over previous
//
#include <hip/hip_runtime.h>
#include <hip/hip_fp16.h>
#include <math.h>

#define NN 50000
#define NE 800000
#define HC 128
#define EMB 64
#define STATS_BLOCKS 64
#define NB 196           // buckets of 256 nodes
#define HIST_BLOCKS 196  // ceil(NE/4096)
#define WPREP_BLOCKS 192 // 3 layers x 64 blocks
#define WT_ROW 136       // padded fp16 W^T row (halves)
#define GEMM_BLOCKS 782  // ceil(NN/64)

typedef _Float16 f16x8 __attribute__((ext_vector_type(8)));
typedef float f32x4 __attribute__((ext_vector_type(4)));

__device__ __forceinline__ float lrelu(float x) { return x > 0.0f ? x : 0.2f * x; }
__device__ __forceinline__ float gelu_f(float x) {
    return 0.5f * x * (1.0f + erff(x * 0.70710678118654752440f));
}
__device__ __forceinline__ float sel4(float4 v, int h) {
    float r = v.x;
    r = (h == 1) ? v.y : r;
    r = (h == 2) ? v.z : r;
    r = (h == 3) ? v.w : r;
    return r;
}
__device__ __forceinline__ f16x8 cvt8(float4 a, float4 b) {
    f16x8 v;
    v[0] = (_Float16)a.x; v[1] = (_Float16)a.y; v[2] = (_Float16)a.z; v[3] = (_Float16)a.w;
    v[4] = (_Float16)b.x; v[5] = (_Float16)b.y; v[6] = (_Float16)b.z; v[7] = (_Float16)b.w;
    return v;
}

// ---- fused frontend: stats | bucket histogram (dst>>8) | W->fp16 W^T prep ----
__global__ void prep_kernel(const float* __restrict__ rq, float* __restrict__ stats,
                            const int* __restrict__ dst, int* __restrict__ bucketCnt,
                            const float* __restrict__ W0, const float* __restrict__ W1,
                            const float* __restrict__ W2, _Float16* __restrict__ wt) {
    __shared__ float ls[4], ls2[4];
    __shared__ int cnt[NB];
    if (blockIdx.x < STATS_BLOCKS) {
        int i = blockIdx.x * 256 + threadIdx.x;
        float s = 0.f, s2 = 0.f;
        for (; i < NN; i += STATS_BLOCKS * 256) {
            float v = rq[i];
            s += v; s2 += v * v;
        }
        #pragma unroll
        for (int off = 32; off > 0; off >>= 1) {
            s  += __shfl_down(s, off);
            s2 += __shfl_down(s2, off);
        }
        int lane = threadIdx.x & 63, wid = threadIdx.x >> 6;
        if (lane == 0) { ls[wid] = s; ls2[wid] = s2; }
        __syncthreads();
        if (threadIdx.x == 0) {
            atomicAdd(&stats[0], ls[0] + ls[1] + ls[2] + ls[3]);
            atomicAdd(&stats[1], ls2[0] + ls2[1] + ls2[2] + ls2[3]);
        }
    } else if (blockIdx.x < STATS_BLOCKS + HIST_BLOCKS) {
        int bb = blockIdx.x - STATS_BLOCKS;
        for (int i = threadIdx.x; i < NB; i += 256) cnt[i] = 0;
        __syncthreads();
        int base = bb * 4096;
        #pragma unroll
        for (int it = 0; it < 16; it++) {
            int i = base + it * 256 + threadIdx.x;
            if (i < NE) atomicAdd(&cnt[dst[i] >> 8], 1);
        }
        __syncthreads();
        for (int i = threadIdx.x; i < NB; i += 256)
            if (cnt[i]) atomicAdd(&bucketCnt[i], cnt[i]);
    } else {
        int bb = blockIdx.x - STATS_BLOCKS - HIST_BLOCKS;   // 0..191
        int l = bb >> 6, blk = bb & 63;
        const float* W = (l == 0) ? W0 : (l == 1) ? W1 : W2;
        int idx = blk * 256 + threadIdx.x;   // 0..16383
        int n = idx >> 7, k = idx & 127;
        wt[(size_t)l * 128 * WT_ROW + n * WT_ROW + k] = (_Float16)W[k * 128 + n];
    }
}

// ---- in-block inclusive scan of bucketCnt into sIncl[256] ----
__device__ __forceinline__ void scan_buckets(const int* __restrict__ bucketCnt,
                                             int* sIncl /*LDS[256]*/) {
    int t = threadIdx.x;
    int v = (t < NB) ? bucketCnt[t] : 0;
    sIncl[t] = v;
    __syncthreads();
    #pragma unroll
    for (int off = 1; off < 256; off <<= 1) {
        int add = (t >= off) ? sIncl[t - off] : 0;
        __syncthreads();
        sIncl[t] += add;
        __syncthreads();
    }
}

// ---- MFMA + epilogue (shared): C from sX@sWt(B in LDS); h store + als/ald ----
__device__ __forceinline__ void mfma_epilogue(_Float16* sWt, _Float16* sX,
        const float* __restrict__ a_src, const float* __restrict__ a_dst,
        __half* __restrict__ h, float* __restrict__ als, float* __restrict__ ald,
        int row0) {
    int t = threadIdx.x;
    int w = t >> 6, l = t & 63;
    int col = l & 15, quad = l >> 4;

    f16x8 afr[4];
    #pragma unroll
    for (int ks = 0; ks < 4; ks++)
        afr[ks] = *(const f16x8*)&sX[(w * 16 + col) * WT_ROW + ks * 32 + quad * 8];

    f32x4 zero = {0.f, 0.f, 0.f, 0.f};
    f32x4 acc[8];
    #pragma unroll
    for (int nt = 0; nt < 8; nt++) acc[nt] = zero;
    #pragma unroll
    for (int nt = 0; nt < 8; nt++) {
        #pragma unroll
        for (int ks = 0; ks < 4; ks++) {
            f16x8 bfr = *(const f16x8*)&sWt[(nt * 16 + col) * WT_ROW + ks * 32 + quad * 8];
            acc[nt] = __builtin_amdgcn_mfma_f32_16x16x32_f16(afr[ks], bfr, acc[nt], 0, 0, 0);
        }
    }
    __syncthreads();   // all MFMA reads of sWt done; reuse as transpose buffer

    _Float16* sOut = sWt;   // [64][136]
    #pragma unroll
    for (int nt = 0; nt < 8; nt++)
        #pragma unroll
        for (int r = 0; r < 4; r++)
            sOut[(w * 16 + quad * 4 + r) * WT_ROW + nt * 16 + col] = (_Float16)acc[nt][r];
    __builtin_amdgcn_wave_barrier();
    #pragma unroll
    for (int i = 0; i < 4; i++) {
        int u = l + 64 * i;          // 0..255
        int r = u >> 4, off = (u & 15) * 8;
        int rr = row0 + w * 16 + r;
        f16x8 v = *(const f16x8*)&sOut[(w * 16 + r) * WT_ROW + off];
        if (rr < NN) *(f16x8*)(h + (size_t)rr * 128 + off) = v;
    }

    float as[8], ad[8];
    #pragma unroll
    for (int nt = 0; nt < 8; nt++) {
        as[nt] = a_src[nt * 16 + col];
        ad[nt] = a_dst[nt * 16 + col];
    }
    #pragma unroll
    for (int r = 0; r < 4; r++) {
        float ps[4], pd[4];
        #pragma unroll
        for (int hd = 0; hd < 4; hd++) {
            ps[hd] = acc[2 * hd][r] * as[2 * hd] + acc[2 * hd + 1][r] * as[2 * hd + 1];
            pd[hd] = acc[2 * hd][r] * ad[2 * hd] + acc[2 * hd + 1][r] * ad[2 * hd + 1];
            ps[hd] += __shfl_xor(ps[hd], 1); pd[hd] += __shfl_xor(pd[hd], 1);
            ps[hd] += __shfl_xor(ps[hd], 2); pd[hd] += __shfl_xor(pd[hd], 2);
            ps[hd] += __shfl_xor(ps[hd], 4); pd[hd] += __shfl_xor(pd[hd], 4);
            ps[hd] += __shfl_xor(ps[hd], 8); pd[hd] += __shfl_xor(pd[hd], 8);
        }
        int rr = row0 + w * 16 + quad * 4 + r;
        if (col == 0 && rr < NN) {
            *(float4*)(als + (size_t)rr * 4) = make_float4(ps[0], ps[1], ps[2], ps[3]);
            *(float4*)(ald + (size_t)rr * 4) = make_float4(pd[0], pd[1], pd[2], pd[3]);
        }
    }
}

// ---- fused dispatch: [gemm0 (x build + GEMM) | binA edge partition] ----
__launch_bounds__(256)
__global__ void gemm0_binA_kernel(const _Float16* __restrict__ wt,
                                  const float* __restrict__ a_src, const float* __restrict__ a_dst,
                                  __half* __restrict__ h, float* __restrict__ als,
                                  float* __restrict__ ald,
                                  const int* __restrict__ label, const float* __restrict__ rq,
                                  const float* __restrict__ emb, const float* __restrict__ reqW,
                                  const float* __restrict__ reqb, const float* __restrict__ stats,
                                  const int* __restrict__ src, const int* __restrict__ dst,
                                  const int* __restrict__ bucketCnt, int* __restrict__ gcur,
                                  int2* __restrict__ edge_tmp) {
    extern __shared__ char smem[];
    if (blockIdx.x >= GEMM_BLOCKS) {
        // -------- binA: partition edges into bucket regions --------
        int bb = blockIdx.x - GEMM_BLOCKS;
        int* sIncl  = (int*)smem;        // 256
        int* sBaseE = sIncl + 256;       // 256
        int* cnt    = sBaseE + 256;      // NB
        int* cur    = cnt + NB;          // NB
        int t = threadIdx.x;
        scan_buckets(bucketCnt, sIncl);
        {
            int v = (t < NB) ? bucketCnt[t] : 0;
            sBaseE[t] = sIncl[t] - v;
        }
        for (int i = t; i < NB; i += 256) cnt[i] = 0;
        __syncthreads();
        int base = bb * 4096;
        int d[16], s[16];
        #pragma unroll
        for (int it = 0; it < 16; it++) {
            int i = base + it * 256 + t;
            bool ok = i < NE;
            d[it] = ok ? dst[i] : -1;
            s[it] = ok ? src[i] : 0;
            if (ok) atomicAdd(&cnt[d[it] >> 8], 1);
        }
        __syncthreads();
        for (int i = t; i < NB; i += 256)
            cur[i] = cnt[i] ? (sBaseE[i] + atomicAdd(&gcur[i], cnt[i])) : 0;
        __syncthreads();
        #pragma unroll
        for (int it = 0; it < 16; it++) {
            if (d[it] >= 0) {
                int b = d[it] >> 8;
                int pos = atomicAdd(&cur[b], 1);
                edge_tmp[pos] = make_int2(s[it], d[it] & 255);
            }
        }
        return;
    }
    // -------- gemm0: build x in LDS from raw inputs, then GEMM --------
    _Float16* sWt = (_Float16*)smem;            // [128][136]
    _Float16* sX  = sWt + 128 * WT_ROW;         // [64][136]
    int t = threadIdx.x;
    int row0 = blockIdx.x * 64;

    {
        const f16x8* g = (const f16x8*)wt;
        f16x8* s = (f16x8*)sWt;
        #pragma unroll
        for (int i = 0; i < 9; i++) {
            int idx = t + 256 * i;
            if (idx < 128 * WT_ROW / 8) s[idx] = g[idx];
        }
    }
    {
        float sum = stats[0], sumsq = stats[1];
        float mean = sum / (float)NN;
        float var = (sumsq - sum * sum / (float)NN) / (float)(NN - 1);
        float inv = 1.0f / (sqrtf(var) + 1e-6f);
        #pragma unroll
        for (int i = 0; i < 4; i++) {
            int idx = t + 256 * i;   // 0..1023 8-half units
            int r = idx >> 4;        // 0..63
            int q = idx & 15;
            int rr = row0 + r;
            f16x8 v;
            #pragma unroll
            for (int j = 0; j < 8; j++) v[j] = (_Float16)0.f;
            if (rr < NN) {
                if (q < 8) {
                    const float4* er = (const float4*)(emb + (size_t)label[rr] * EMB);
                    v = cvt8(er[q * 2], er[q * 2 + 1]);
                } else {
                    int j4 = (q - 8) * 2;
                    float4 w0 = ((const float4*)reqW)[j4],     b0 = ((const float4*)reqb)[j4];
                    float4 w1 = ((const float4*)reqW)[j4 + 1], b1 = ((const float4*)reqb)[j4 + 1];
                    float r2 = (rq[rr] - mean) * inv;
                    v = cvt8(make_float4(r2 * w0.x + b0.x, r2 * w0.y + b0.y,
                                         r2 * w0.z + b0.z, r2 * w0.w + b0.w),
                             make_float4(r2 * w1.x + b1.x, r2 * w1.y + b1.y,
                                         r2 * w1.z + b1.z, r2 * w1.w + b1.w));
                }
            }
            *(f16x8*)&sX[r * WT_ROW + q * 8] = v;
        }
    }
    __syncthreads();
    mfma_epilogue(sWt, sX, a_src, a_dst, h, als, ald, row0);
}

// ------- binB: per-bucket local counting sort -> row_start + src_sorted -------
__global__ void binB_kernel(const int2* __restrict__ edge_tmp, const int* __restrict__ bucketCnt,
                            int* __restrict__ row_start, int* __restrict__ src_sorted) {
    __shared__ int sIncl[256];
    __shared__ int ldeg[256];
    __shared__ int lexcl[256];
    __shared__ int lcur[256];
    __shared__ int s_base, s_end;
    int b = blockIdx.x, t = threadIdx.x;
    scan_buckets(bucketCnt, sIncl);
    if (t == 0) {
        s_end = sIncl[b];
        s_base = sIncl[b] - bucketCnt[b];
    }
    ldeg[t] = 0;
    __syncthreads();
    int base = s_base, endb = s_end;
    for (int i = base + t; i < endb; i += 256)
        atomicAdd(&ldeg[edge_tmp[i].y], 1);
    __syncthreads();
    int v = ldeg[t];
    lexcl[t] = v;
    __syncthreads();
    #pragma unroll
    for (int off = 1; off < 256; off <<= 1) {
        int add = (t >= off) ? lexcl[t - off] : 0;
        __syncthreads();
        lexcl[t] += add;
        __syncthreads();
    }
    int excl = lexcl[t] - v;
    int node = b * 256 + t;
    if (node <= NN) row_start[node] = base + excl;
    lcur[t] = excl;
    __syncthreads();
    for (int i = base + t; i < endb; i += 256) {
        int2 e = edge_tmp[i];
        int pos = atomicAdd(&lcur[e.y], 1);
        src_sorted[base + pos] = e.x;
    }
}

// ---- fused layer, SINGLE-WAVE blocks (R7 verified-best form) ----
// All logic is wave-local (no __syncthreads). 64-thread blocks keep LDS at
// 8.5 KB/block -> 18 blocks/CU (vs R8's 21 KB -> 7: occupancy 18.8->13.9%,
// BW 2.05->1.74 TB/s — waves x in-flight-loads product rules this kernel).
__launch_bounds__(64, 3)
__global__ void layer_fused_kernel(const __half* __restrict__ hp, const float* __restrict__ alsp,
                                   const float* __restrict__ aldp, const int* __restrict__ row_start,
                                   const int* __restrict__ src_sorted, const float* __restrict__ biasp,
                                   const _Float16* __restrict__ wt,
                                   const float* __restrict__ a_src, const float* __restrict__ a_dst,
                                   __half* __restrict__ ho, float* __restrict__ also_,
                                   float* __restrict__ aldo) {
    __shared__ _Float16 sX[16 * WT_ROW];     // 4352 B (agg out = GEMM A; reused as sOut)
    __shared__ int2 lds_sp[4][130];          // 4160 B p-stash
    int lane = threadIdx.x;                  // 0..63
    int g    = lane >> 4;   // node sub-index in round == quad in GEMM
    int cg   = lane & 15;   // channel group       == col  in GEMM
    int c0   = cg * 8;
    int head = cg >> 2;
    int row0 = blockIdx.x * 16;              // 3125 blocks * 16 = 50000 exactly

    // ---- agg phase: 4 rounds x 4 nodes ----
    for (int round = 0; round < 4; round++) {
        int nb = row0 + round * 4;
        int node = nb + g;

        int rs = row_start[node];
        int re = row_start[node + 1];
        int start = __shfl(rs, 0);
        int end   = __shfl(re, 48);
        int b1 = __shfl(rs, 16), b2 = __shfl(rs, 32), b3 = __shfl(rs, 48);

        float4 adv = *(const float4*)(aldp + (size_t)node * 4);
        float4 avs = *(const float4*)(alsp + (size_t)node * 4);

        float p_self = __expf(lrelu(sel4(avs, head) + sel4(adv, head)));
        float s_sum = p_self;
        float acc[8];
        {
            f16x8 hv = *(const f16x8*)(hp + (size_t)node * 128 + c0);
            #pragma unroll
            for (int j = 0; j < 8; j++) acc[j] = (float)hv[j] * p_self;
        }

        for (int base = start; base < end; base += 128) {
            int j0 = base + lane, j1 = base + 64 + lane;
            bool v0 = j0 < end, v1 = j1 < end;
            int my0 = v0 ? src_sorted[j0] : 0;
            int my1 = v1 ? src_sorted[j1] : 0;
            float4 av0 = *(const float4*)(alsp + (size_t)my0 * 4);
            float4 av1 = *(const float4*)(alsp + (size_t)my1 * 4);
            int o0 = (j0 >= b1) + (j0 >= b2) + (j0 >= b3);
            int o1 = (j1 >= b1) + (j1 >= b2) + (j1 >= b3);
            float4 d0 = *(const float4*)(aldp + (size_t)(nb + (o0 > 3 ? 3 : o0)) * 4);
            float4 d1 = *(const float4*)(aldp + (size_t)(nb + (o1 > 3 ? 3 : o1)) * 4);
            lds_sp[0][lane] = make_int2(my0, __float_as_int(__expf(lrelu(av0.x + d0.x))));
            lds_sp[1][lane] = make_int2(my0, __float_as_int(__expf(lrelu(av0.y + d0.y))));
            lds_sp[2][lane] = make_int2(my0, __float_as_int(__expf(lrelu(av0.z + d0.z))));
            lds_sp[3][lane] = make_int2(my0, __float_as_int(__expf(lrelu(av0.w + d0.w))));
            lds_sp[0][64 + lane] = make_int2(my1, __float_as_int(__expf(lrelu(av1.x + d1.x))));
            lds_sp[1][64 + lane] = make_int2(my1, __float_as_int(__expf(lrelu(av1.y + d1.y))));
            lds_sp[2][64 + lane] = make_int2(my1, __float_as_int(__expf(lrelu(av1.z + d1.z))));
            lds_sp[3][64 + lane] = make_int2(my1, __float_as_int(__expf(lrelu(av1.w + d1.w))));
            __builtin_amdgcn_wave_barrier();

            int lo  = rs > base ? rs : base;
            int hiw = base + 128;
            int hi  = re < hiw ? re : hiw;
            for (int k = lo; k < hi; k += 16) {
                float p[16];
                const __half* ap[16];
                #pragma unroll
                for (int i = 0; i < 16; i++) {
                    int e = k + i;
                    bool val = e < hi;
                    int ec = (val ? e : hi - 1) - base;
                    int2 sp = lds_sp[head][ec];
                    p[i] = val ? __int_as_float(sp.y) : 0.f;
                    ap[i] = hp + (size_t)sp.x * 128 + c0;
                }
                f16x8 raw[16];
                #pragma unroll
                for (int i = 0; i < 16; i++)
                    raw[i] = *(const f16x8*)ap[i];
                #pragma unroll
                for (int i = 0; i < 16; i++) {
                    s_sum += p[i];
                    #pragma unroll
                    for (int jj = 0; jj < 8; jj++)
                        acc[jj] += (float)raw[i][jj] * p[i];
                }
            }
            __builtin_amdgcn_wave_barrier();
        }

        float invs = 1.0f / (s_sum + 1e-16f);
        float4 bv0 = *(const float4*)(biasp + c0);
        float4 bv1 = *(const float4*)(biasp + c0 + 4);
        float ob[8] = {bv0.x, bv0.y, bv0.z, bv0.w, bv1.x, bv1.y, bv1.z, bv1.w};
        f16x8 o;
        #pragma unroll
        for (int jj = 0; jj < 8; jj++)
            o[jj] = (_Float16)gelu_f(acc[jj] * invs + ob[jj]);
        *(f16x8*)&sX[(round * 4 + g) * WT_ROW + c0] = o;
    }
    __builtin_amdgcn_wave_barrier();

    // ---- GEMM phase: A from sX (rows 0..15), B from L2-hot global wt ----
    int col = cg, quad = g;
    f16x8 afr[4];
    #pragma unroll
    for (int ks = 0; ks < 4; ks++)
        afr[ks] = *(const f16x8*)&sX[col * WT_ROW + ks * 32 + quad * 8];
    __builtin_amdgcn_wave_barrier();

    f32x4 zero = {0.f, 0.f, 0.f, 0.f};
    f32x4 acc2[8];
    #pragma unroll
    for (int nt = 0; nt < 8; nt++) acc2[nt] = zero;
    #pragma unroll
    for (int nt = 0; nt < 8; nt++) {
        #pragma unroll
        for (int ks = 0; ks < 4; ks++) {
            f16x8 bfr = *(const f16x8*)&wt[(nt * 16 + col) * WT_ROW + ks * 32 + quad * 8];
            acc2[nt] = __builtin_amdgcn_mfma_f32_16x16x32_f16(afr[ks], bfr, acc2[nt], 0, 0, 0);
        }
    }

    // transpose via sX rows (A-frags already consumed)
    _Float16* sOut = sX;
    #pragma unroll
    for (int nt = 0; nt < 8; nt++)
        #pragma unroll
        for (int r = 0; r < 4; r++)
            sOut[(quad * 4 + r) * WT_ROW + nt * 16 + col] = (_Float16)acc2[nt][r];
    __builtin_amdgcn_wave_barrier();
    #pragma unroll
    for (int i = 0; i < 4; i++) {
        int u = lane + 64 * i;       // 0..255 = 16 rows x 16 col-groups
        int r = u >> 4, off2 = (u & 15) * 8;
        int rr = row0 + r;
        f16x8 v = *(const f16x8*)&sOut[r * WT_ROW + off2];
        if (rr < NN) *(f16x8*)(ho + (size_t)rr * 128 + off2) = v;
    }

    float as[8], ad[8];
    #pragma unroll
    for (int nt = 0; nt < 8; nt++) {
        as[nt] = a_src[nt * 16 + col];
        ad[nt] = a_dst[nt * 16 + col];
    }
    #pragma unroll
    for (int r = 0; r < 4; r++) {
        float ps[4], pd[4];
        #pragma unroll
        for (int hd = 0; hd < 4; hd++) {
            ps[hd] = acc2[2 * hd][r] * as[2 * hd] + acc2[2 * hd + 1][r] * as[2 * hd + 1];
            pd[hd] = acc2[2 * hd][r] * ad[2 * hd] + acc2[2 * hd + 1][r] * ad[2 * hd + 1];
            ps[hd] += __shfl_xor(ps[hd], 1); pd[hd] += __shfl_xor(pd[hd], 1);
            ps[hd] += __shfl_xor(ps[hd], 2); pd[hd] += __shfl_xor(pd[hd], 2);
            ps[hd] += __shfl_xor(ps[hd], 4); pd[hd] += __shfl_xor(pd[hd], 4);
            ps[hd] += __shfl_xor(ps[hd], 8); pd[hd] += __shfl_xor(pd[hd], 8);
        }
        int rr = row0 + quad * 4 + r;
        if (col == 0 && rr < NN) {
            *(float4*)(also_ + (size_t)rr * 4) = make_float4(ps[0], ps[1], ps[2], ps[3]);
            *(float4*)(aldo + (size_t)rr * 4) = make_float4(pd[0], pd[1], pd[2], pd[3]);
        }
    }
}

// ---------------- final per-node softmax aggregation -> fp32 out ----------------
__launch_bounds__(256)
__global__ void agg_final_kernel(const __half* __restrict__ h, const float* __restrict__ als_,
                                 const float* __restrict__ ald_, const int* __restrict__ row_start,
                                 const int* __restrict__ src_sorted, const float* __restrict__ bias,
                                 float* __restrict__ outf) {
    __shared__ int2 lds_sp[4][4][130];   // [wave][head][slot] = {src, p_bits}
    int wid  = threadIdx.x >> 6;
    int lane = threadIdx.x & 63;
    int g    = lane >> 4;
    int cg   = lane & 15;
    int c0   = cg * 8;
    int head = cg >> 2;

    int nb = blockIdx.x * 16 + wid * 4;   // 3125 blocks * 16 = 50000 exactly
    if (nb >= NN) return;
    int node = nb + g;

    int rs = row_start[node];
    int re = row_start[node + 1];
    int start = __shfl(rs, 0);
    int end   = __shfl(re, 48);
    int b1 = __shfl(rs, 16), b2 = __shfl(rs, 32), b3 = __shfl(rs, 48);

    float4 adv = *(const float4*)(ald_ + (size_t)node * 4);
    float4 avs = *(const float4*)(als_ + (size_t)node * 4);

    float p_self = __expf(lrelu(sel4(avs, head) + sel4(adv, head)));
    float s_sum = p_self;
    float acc[8];
    {
        f16x8 hv = *(const f16x8*)(h + (size_t)node * 128 + c0);
        #pragma unroll
        for (int j = 0; j < 8; j++) acc[j] = (float)hv[j] * p_self;
    }

    for (int base = start; base < end; base += 128) {
        int j0 = base + lane, j1 = base + 64 + lane;
        bool v0 = j0 < end, v1 = j1 < end;
        int my0 = v0 ? src_sorted[j0] : 0;
        int my1 = v1 ? src_sorted[j1] : 0;
        float4 av0 = *(const float4*)(als_ + (size_t)my0 * 4);
        float4 av1 = *(const float4*)(als_ + (size_t)my1 * 4);
        int o0 = (j0 >= b1) + (j0 >= b2) + (j0 >= b3);
        int o1 = (j1 >= b1) + (j1 >= b2) + (j1 >= b3);
        float4 d0 = *(const float4*)(ald_ + (size_t)(nb + (o0 > 3 ? 3 : o0)) * 4);
        float4 d1 = *(const float4*)(ald_ + (size_t)(nb + (o1 > 3 ? 3 : o1)) * 4);
        lds_sp[wid][0][lane] = make_int2(my0, __float_as_int(__expf(lrelu(av0.x + d0.x))));
        lds_sp[wid][1][lane] = make_int2(my0, __float_as_int(__expf(lrelu(av0.y + d0.y))));
        lds_sp[wid][2][lane] = make_int2(my0, __float_as_int(__expf(lrelu(av0.z + d0.z))));
        lds_sp[wid][3][lane] = make_int2(my0, __float_as_int(__expf(lrelu(av0.w + d0.w))));
        lds_sp[wid][0][64 + lane] = make_int2(my1, __float_as_int(__expf(lrelu(av1.x + d1.x))));
        lds_sp[wid][1][64 + lane] = make_int2(my1, __float_as_int(__expf(lrelu(av1.y + d1.y))));
        lds_sp[wid][2][64 + lane] = make_int2(my1, __float_as_int(__expf(lrelu(av1.z + d1.z))));
        lds_sp[wid][3][64 + lane] = make_int2(my1, __float_as_int(__expf(lrelu(av1.w + d1.w))));
        __builtin_amdgcn_wave_barrier();

        int lo  = rs > base ? rs : base;
        int hiw = base + 128;
        int hi  = re < hiw ? re : hiw;
        for (int k = lo; k < hi; k += 16) {
            float p[16];
            const __half* ap[16];
            #pragma unroll
            for (int i = 0; i < 16; i++) {
                int e = k + i;
                bool val = e < hi;
                int ec = (val ? e : hi - 1) - base;
                int2 sp = lds_sp[wid][head][ec];
                p[i] = val ? __int_as_float(sp.y) : 0.f;
                ap[i] = h + (size_t)sp.x * 128 + c0;
            }
            f16x8 raw[16];
            #pragma unroll
            for (int i = 0; i < 16; i++)
                raw[i] = *(const f16x8*)ap[i];
            #pragma unroll
            for (int i = 0; i < 16; i++) {
                s_sum += p[i];
                #pragma unroll
                for (int jj = 0; jj < 8; jj++)
                    acc[jj] += (float)raw[i][jj] * p[i];
            }
        }
        __builtin_amdgcn_wave_barrier();
    }

    float invs = 1.0f / (s_sum + 1e-16f);
    float4 bv0 = *(const float4*)(bias + c0);
    float4 bv1 = *(const float4*)(bias + c0 + 4);
    float ob[8] = {bv0.x, bv0.y, bv0.z, bv0.w, bv1.x, bv1.y, bv1.z, bv1.w};
    float o8[8];
    #pragma unroll
    for (int jj = 0; jj < 8; jj++) o8[jj] = gelu_f(acc[jj] * invs + ob[jj]);
    float* op = outf + (size_t)node * 128 + c0;
    *(float4*)op       = make_float4(o8[0], o8[1], o8[2], o8[3]);
    *(float4*)(op + 4) = make_float4(o8[4], o8[5], o8[6], o8[7]);
}

extern "C" void kernel_launch(void* const* d_in, const int* in_sizes, int n_in,
                              void* d_out, int out_size, void* d_ws, size_t ws_size,
                              hipStream_t stream) {
    const int*   label = (const int*)d_in[0];
    const int*   eidx  = (const int*)d_in[1];          // [2, NE]
    const float* rq    = (const float*)d_in[3];
    const float* emb   = (const float*)d_in[4];
    const float* reqW  = (const float*)d_in[5];
    const float* reqb  = (const float*)d_in[6];
    const float* W[3]    = {(const float*)d_in[7],  (const float*)d_in[11], (const float*)d_in[15]};
    const float* asrc[3] = {(const float*)d_in[8],  (const float*)d_in[12], (const float*)d_in[16]};
    const float* adst[3] = {(const float*)d_in[9],  (const float*)d_in[13], (const float*)d_in[17]};
    const float* bias[3] = {(const float*)d_in[10], (const float*)d_in[14], (const float*)d_in[18]};

    const int* e_src = eidx;
    const int* e_dst = eidx + NE;

    char* ws = (char*)d_ws;
    size_t off = 0;
    auto A = [&](size_t n) { size_t o = off; off += (n + 255) & ~(size_t)255; return o; };
    size_t o_bcnt  = A(256 * 4);               // zeroed
    size_t o_gcur  = A(256 * 4);               // zeroed
    size_t o_stats = A(8);                     // zeroed
    size_t zero_bytes = off;
    size_t o_row   = A((size_t)(NN + 1) * 4);
    size_t o_etmp  = A((size_t)NE * 8);
    size_t o_srcS  = A((size_t)NE * 4);
    size_t o_wt    = A((size_t)3 * 128 * WT_ROW * 2);
    size_t o_h0    = A((size_t)NN * 128 * 2);  // fp16
    size_t o_h1    = A((size_t)NN * 128 * 2);  // fp16
    size_t o_als0  = A((size_t)NN * 4 * 4);
    size_t o_ald0  = A((size_t)NN * 4 * 4);
    size_t o_als1  = A((size_t)NN * 4 * 4);
    size_t o_ald1  = A((size_t)NN * 4 * 4);
    (void)ws_size; (void)n_in; (void)in_sizes; (void)out_size;

    int*      bcnt  = (int*)(ws + o_bcnt);
    int*      gcur  = (int*)(ws + o_gcur);
    float*    stats = (float*)(ws + o_stats);
    int*      rowst = (int*)(ws + o_row);
    int2*     etmp  = (int2*)(ws + o_etmp);
    int*      srcS  = (int*)(ws + o_srcS);
    _Float16* wt    = (_Float16*)(ws + o_wt);
    __half*   h0    = (__half*)(ws + o_h0);
    __half*   h1    = (__half*)(ws + o_h1);
    float*    als0  = (float*)(ws + o_als0);
    float*    ald0  = (float*)(ws + o_ald0);
    float*    als1  = (float*)(ws + o_als1);
    float*    ald1  = (float*)(ws + o_ald1);

    (void)hipMemsetAsync(ws, 0, zero_bytes, stream);

    const int smem_l0 = (128 + 64) * WT_ROW * 2;   // 52224 B

    // 1) stats | bucket histogram | W^T fp16 prep
    prep_kernel<<<STATS_BLOCKS + HIST_BLOCKS + WPREP_BLOCKS, 256, 0, stream>>>(
        rq, stats, e_dst, bcnt, W[0], W[1], W[2], wt);
    // 2) [gemm0 | binA]  (both depend only on prep; independent of each other)
    gemm0_binA_kernel<<<GEMM_BLOCKS + HIST_BLOCKS, 256, smem_l0, stream>>>(
        wt, asrc[0], adst[0], h0, als0, ald0, label, rq, emb, reqW, reqb, stats,
        e_src, e_dst, bcnt, gcur, etmp);
    // 3) binB: per-bucket counting sort -> row_start + src_sorted
    binB_kernel<<<NB, 256, 0, stream>>>(etmp, bcnt, rowst, srcS);
    // 4) fused layer 1 (single-wave blocks): agg(h0) -> gemm(W1) -> h1
    layer_fused_kernel<<<(NN + 15) / 16, 64, 0, stream>>>(
        h0, als0, ald0, rowst, srcS, bias[0],
        wt + (size_t)1 * 128 * WT_ROW, asrc[1], adst[1], h1, als1, ald1);
    // 5) fused layer 2 (single-wave blocks): agg(h1) -> gemm(W2) -> h0
    layer_fused_kernel<<<(NN + 15) / 16, 64, 0, stream>>>(
        h1, als1, ald1, rowst, srcS, bias[1],
        wt + (size_t)2 * 128 * WT_ROW, asrc[2], adst[2], h0, als0, ald0);
    // 6) final agg -> fp32 output
    agg_final_kernel<<<(NN + 15) / 16, 256, 0, stream>>>(
        h0, als0, ald0, rowst, srcS, bias[2], (float*)d_out);
}